// Round 6
// baseline (548.107 us; speedup 1.0000x reference)
//
#include <hip/hip_runtime.h>
#include <hip/hip_bf16.h>

typedef __hip_bfloat16 BF16;
typedef __attribute__((ext_vector_type(8))) short bf16x8;
typedef __attribute__((ext_vector_type(4))) float f32x4;
typedef __attribute__((ext_vector_type(4))) int int4v;

#define MTOK 12608      // 64*197 tokens
#define D_IN 768
#define KAUG 832        // 768 + 64 (E*R)
#define N_QKV 2304

#define AS1 __attribute__((address_space(1)))
#define AS3 __attribute__((address_space(3)))
#define SB0() __builtin_amdgcn_sched_barrier(0)

// ---------------- prep kernels ----------------
__global__ __launch_bounds__(256) void prep_waug_k(const float* __restrict__ qkv_w,
                                                   const float* __restrict__ lora_b,
                                                   BF16* __restrict__ Waug) {
  int idx = blockIdx.x*256 + threadIdx.x;
  if (idx >= N_QKV*KAUG) return;
  int k = idx / KAUG, c = idx - k*KAUG;
  float v = (c < D_IN) ? qkv_w[k*D_IN + c] : lora_b[(size_t)(c - D_IN)*N_QKV + k];
  Waug[idx] = (BF16)v;
}

__global__ __launch_bounds__(256) void prep_pb_k(const float* __restrict__ proj_w,
                                                 BF16* __restrict__ Pb) {
  int idx = blockIdx.x*256 + threadIdx.x;
  if (idx < D_IN*D_IN) Pb[idx] = (BF16)proj_w[idx];
}

__global__ __launch_bounds__(256) void prep_lat_k(const float* __restrict__ lora_a,
                                                  BF16* __restrict__ LAt) {
  int idx = blockIdx.x*256 + threadIdx.x;
  if (idx >= 64*D_IN) return;
  int j = idx / D_IN, d = idx - j*D_IN;
  LAt[idx] = (BF16)lora_a[(size_t)(j >> 3)*6144 + d*8 + (j & 7)];
}

// ---------------- token prep: bf16 cast + gate softmax ----------------
__global__ __launch_bounds__(256) void token_prep_k(const float* __restrict__ tokens,
                                                    const float* __restrict__ gate_w,
                                                    BF16* __restrict__ Aaug,
                                                    float* __restrict__ gates) {
  int w = blockIdx.x*4 + (threadIdx.x >> 6);
  int lane = threadIdx.x & 63;
  if (w >= MTOK) return;
  const float* x = tokens + (size_t)w*D_IN;
  float xv[12];
  #pragma unroll
  for (int i=0;i<12;++i) xv[i] = x[lane + 64*i];
  #pragma unroll
  for (int i=0;i<12;++i) Aaug[(size_t)w*KAUG + lane + 64*i] = (BF16)xv[i];
  float g[8] = {0,0,0,0,0,0,0,0};
  #pragma unroll
  for (int i=0;i<12;++i) {
    int d = lane + 64*i;
    #pragma unroll
    for (int e=0;e<8;++e) g[e] += xv[i]*gate_w[e*D_IN + d];
  }
  #pragma unroll
  for (int e=0;e<8;++e) {
    #pragma unroll
    for (int off=32; off; off >>= 1) g[e] += __shfl_xor(g[e], off);
  }
  float mx = g[0];
  #pragma unroll
  for (int e=1;e<8;++e) mx = fmaxf(mx, g[e]);
  float pe[8]; float ssum = 0.f;
  #pragma unroll
  for (int e=0;e<8;++e) { pe[e] = __expf(g[e]-mx); ssum += pe[e]; }
  float inv = 1.f/ssum;
  if (lane < 8) {
    float val = 0.f;
    #pragma unroll
    for (int e=0;e<8;++e) val = (lane==e) ? pe[e]*inv : val;
    gates[(size_t)w*8 + lane] = val;
  }
}

// ---------------- small 2-phase GEMM-BT (h-GEMM only) ----------------
template<int ROWS>
__device__ __forceinline__ void stage_bt(const BF16* __restrict__ g, int ldg, int row0, int M,
                                         BF16* lds, int kbase, int t) {
  constexpr int NIT = ROWS*8/256;
  #pragma unroll
  for (int it=0; it<NIT; ++it) {
    int c = it*256 + t;
    int r = c >> 3, kc = c & 7;
    int rg = row0 + r;
    rg = (rg < M) ? rg : (M-1);
    const BF16* gp = g + (size_t)rg*ldg + kbase + kc*8;
    BF16* lp = lds + (it*256 + (t & ~63))*8;
    __builtin_amdgcn_global_load_lds((const AS1 void*)gp, (AS3 void*)lp, 16, 0, 0);
  }
}

template<int BM, int BN, int EPI>
__global__ __launch_bounds__(256,3) void gemm_bt_k(const BF16* __restrict__ A, int lda,
                                                   const BF16* __restrict__ Bt, int ldb,
                                                   const float* __restrict__ aux,
                                                   void* __restrict__ Cv, int ldc,
                                                   int M, int K) {
  constexpr int BK = 64;
  constexpr int WM = BM/2, WN = BN/2;
  constexpr int MF = WM/16, NF = WN/16;
  __shared__ BF16 Al[BM*BK];
  __shared__ BF16 Bl[BN*BK];
  const int n0 = blockIdx.x*BN, m0 = blockIdx.y*BM;
  const int t = threadIdx.x, lane = t & 63, wid = t >> 6;
  const int wm = (wid >> 1)*WM, wn = (wid & 1)*WN;
  f32x4 acc[MF][NF] = {};
  const int KT = K/BK;
  for (int kt=0; kt<KT; ++kt) {
    stage_bt<BM>(A, lda, m0, M, Al, kt*BK, t);
    stage_bt<BN>(Bt, ldb, n0, 1<<30, Bl, kt*BK, t);
    __syncthreads();
    #pragma unroll
    for (int kk=0; kk<2; ++kk) {
      bf16x8 a[MF], b[NF];
      const int col = kk*32 + (lane >> 4)*8;
      #pragma unroll
      for (int m=0;m<MF;++m) a[m] = *(const bf16x8*)(Al + (wm + m*16 + (lane & 15))*BK + col);
      #pragma unroll
      for (int n=0;n<NF;++n) b[n] = *(const bf16x8*)(Bl + (wn + n*16 + (lane & 15))*BK + col);
      #pragma unroll
      for (int m=0;m<MF;++m)
        #pragma unroll
        for (int n=0;n<NF;++n)
          acc[m][n] = __builtin_amdgcn_mfma_f32_16x16x32_bf16(a[m], b[n], acc[m][n], 0, 0, 0);
    }
    __syncthreads();
  }
  #pragma unroll
  for (int m=0;m<MF;++m) {
    #pragma unroll
    for (int n=0;n<NF;++n) {
      const int rb = m0 + wm + m*16 + (lane >> 4)*4;
      const int c = n0 + wn + n*16 + (lane & 15);
      #pragma unroll
      for (int j=0;j<4;++j) {
        const int r = rb + j;
        if (r < M) {
          float v = acc[m][n][j];
          if (EPI == 0) {
            v *= aux[(size_t)r*8 + (c >> 3)];
            ((BF16*)Cv)[(size_t)r*ldc + c] = (BF16)v;
          } else if (EPI == 1) {
            v += aux[c];
            ((BF16*)Cv)[(size_t)r*ldc + c] = (BF16)v;
          } else {
            v += aux[c];
            ((float*)Cv)[(size_t)r*ldc + c] = v;
          }
        }
      }
    }
  }
}

// ---------------- 128x128 2-phase double-buffered GEMM-BT (proj) -----
template<int EPI, int NBN, int LDA, int LDB, int LDC>
__global__ __launch_bounds__(256,2) void gemm2_k(const BF16* __restrict__ A,
                                                 const BF16* __restrict__ Bt,
                                                 const float* __restrict__ bias,
                                                 void* __restrict__ Cv,
                                                 int M, int K) {
  __shared__ BF16 Lsh[2][2][8192];          // [buf][A,B][128*64]
  const int t = threadIdx.x, lane = t & 63, wid = t >> 6;
  const int nwg = gridDim.x;
  const int q8 = nwg >> 3, r8 = nwg & 7;
  const int xcd = blockIdx.x & 7, pos = blockIdx.x >> 3;
  const int wg = (xcd < r8 ? xcd*(q8+1) : r8*(q8+1) + (xcd - r8)*q8) + pos;
  const int mb = wg / NBN, nb = wg - mb*NBN;
  const int m0 = mb*128, n0 = nb*128;
  const int KT = K/64;
  const int q4 = lane & 15;
  const int wm = (wid >> 1)*64, wn = (wid & 1)*64;

  const BF16 *sA[4], *sB[4];
  #pragma unroll
  for (int it=0; it<4; ++it) {
    int c = it*256 + t;
    int r = c >> 3, p = c & 7;
    int sc = p ^ (r & 7);
    int ra = m0 + r; ra = ra < M ? ra : M-1;
    sA[it] = A  + (size_t)ra*LDA + sc*8;
    sB[it] = Bt + (size_t)(n0 + r)*LDB + sc*8;
  }
  auto stageAB = [&](int buf, int tile) {
    #pragma unroll
    for (int it=0; it<4; ++it)
      __builtin_amdgcn_global_load_lds((const AS1 void*)(sA[it] + tile*64),
        (AS3 void*)(&Lsh[buf][0][0] + (it*256 + (t & ~63))*8), 16, 0, 0);
    #pragma unroll
    for (int it=0; it<4; ++it)
      __builtin_amdgcn_global_load_lds((const AS1 void*)(sB[it] + tile*64),
        (AS3 void*)(&Lsh[buf][1][0] + (it*256 + (t & ~63))*8), 16, 0, 0);
  };

  const int sw = (q4 & 7) << 3;
  const int ck[2] = { (((lane >> 4)*8)) ^ sw, ((32 + (lane >> 4)*8)) ^ sw };

  f32x4 acc[4][4] = {};
  stageAB(0, 0);
  asm volatile("s_waitcnt vmcnt(0)" ::: "memory"); SB0();
  __builtin_amdgcn_s_barrier();

  for (int kt = 0; kt < KT; ++kt) {
    const int buf = kt & 1;
    if (kt+1 < KT) stageAB(buf^1, kt+1);
    bf16x8 a[4][2], b[4][2];
    #pragma unroll
    for (int m=0;m<4;++m)
      #pragma unroll
      for (int kk=0;kk<2;++kk)
        a[m][kk] = *(const bf16x8*)(&Lsh[buf][0][0] + (wm + m*16 + q4)*64 + ck[kk]);
    #pragma unroll
    for (int n=0;n<4;++n)
      #pragma unroll
      for (int kk=0;kk<2;++kk)
        b[n][kk] = *(const bf16x8*)(&Lsh[buf][1][0] + (wn + n*16 + q4)*64 + ck[kk]);
    asm volatile("s_waitcnt lgkmcnt(0)" ::: "memory"); SB0();
    __builtin_amdgcn_s_setprio(1);
    #pragma unroll
    for (int kk=0;kk<2;++kk)
      #pragma unroll
      for (int m=0;m<4;++m)
        #pragma unroll
        for (int n=0;n<4;++n)
          acc[m][n] = __builtin_amdgcn_mfma_f32_16x16x32_bf16(a[m][kk], b[n][kk], acc[m][n], 0,0,0);
    __builtin_amdgcn_s_setprio(0);
    SB0();
    if (kt+1 < KT) asm volatile("s_waitcnt vmcnt(0)" ::: "memory");
    SB0();
    __builtin_amdgcn_s_barrier();
  }

  float bv[4];
  #pragma unroll
  for (int n=0;n<4;++n) bv[n] = bias[n0 + wn + n*16 + q4];
  #pragma unroll
  for (int m=0;m<4;++m) {
    #pragma unroll
    for (int j=0;j<4;++j) {
      const int r = m0 + wm + m*16 + (lane >> 4)*4 + j;
      if (r < M) {
        #pragma unroll
        for (int n=0;n<4;++n) {
          float v = acc[m][n][j] + bv[n];
          const size_t idx = (size_t)r*LDC + n0 + wn + n*16 + q4;
          if (EPI == 1) ((BF16*)Cv)[idx] = (BF16)v;
          else          ((float*)Cv)[idx] = v;
        }
      }
    }
  }
}

// ---------------- 256x256 pipelined GEMM-BT + diagnostic variants ----------
// VAR 0: real. VAR 1: stage-only w/ full wait+barrier skeleton. VAR 2:
// stage-only, no waits/barriers (raw TA throughput). VAR 3: ds_read+MFMA
// only on zeroed LDS (no staging). VAR!=0 repeats the K-loop REP times and
// writes a scalar per thread to diag.
template<int EPI, int NBN, int LDA, int LDB, int LDC, int VAR, int REP>
__global__ __launch_bounds__(512,1) void gemm8_k(const BF16* __restrict__ A,
                                                 const BF16* __restrict__ Bt,
                                                 const float* __restrict__ bias,
                                                 void* __restrict__ Cv,
                                                 float* __restrict__ diag,
                                                 int M, int K) {
  __shared__ BF16 Lsh[2][2][16384];        // [buf][op A=0,B=1][256*64]
  const int t = threadIdx.x, lane = t & 63, wid = t >> 6;
  const int nwg = gridDim.x;
  const int q8 = nwg >> 3, r8 = nwg & 7;
  const int xcd = blockIdx.x & 7, pos = blockIdx.x >> 3;
  const int wg = (xcd < r8 ? xcd*(q8+1) : r8*(q8+1) + (xcd - r8)*q8) + pos;
  const int mb = wg / NBN, nb = wg - mb*NBN;
  const int m0 = mb*256, n0 = nb*256;
  const int KT = K/64;

  const int q4 = lane & 15;
  const int hA = wid >> 2;
  const int wm = hA*128;
  const int wn = (wid & 3)*64;
  const int hB = wn >> 7;

  const int rl = lane >> 3;
  const int chunk = (lane & 7) ^ rl;
  const BF16* sA0[2]; const BF16* sA1[2]; const BF16* sB0[2]; const BF16* sB1[2];
  #pragma unroll
  for (int c=0;c<2;++c) {
    int s8 = (wid*2 + c)*8 + rl;
    int ra0 = m0 + s8;       ra0 = ra0 < M ? ra0 : M-1;
    int ra1 = m0 + 128 + s8; ra1 = ra1 < M ? ra1 : M-1;
    sA0[c] = A + (size_t)ra0*LDA + chunk*8;
    sA1[c] = A + (size_t)ra1*LDA + chunk*8;
    sB0[c] = Bt + (size_t)(n0 + s8)*LDB + chunk*8;
    sB1[c] = Bt + (size_t)(n0 + 128 + s8)*LDB + chunk*8;
  }
  auto stage = [&](const BF16* const* src, BF16* ldsHalf, int tile) {
    #pragma unroll
    for (int c=0;c<2;++c)
      __builtin_amdgcn_global_load_lds(
        (const AS1 void*)(src[c] + tile*64),
        (AS3 void*)(ldsHalf + (wid*2 + c)*512), 16, 0, 0);
  };

  const int sw = (lane & 7) << 3;
  const int ck0 = ((lane >> 4)*8) ^ sw;
  const int ck1 = (32 + (lane >> 4)*8) ^ sw;
  const BF16* rA[2][2]; const BF16* rB[2][2];
  #pragma unroll
  for (int bu=0;bu<2;++bu) {
    rA[bu][0] = &Lsh[bu][0][hA*8192 + q4*64 + ck0];
    rA[bu][1] = &Lsh[bu][0][hA*8192 + q4*64 + ck1];
    rB[bu][0] = &Lsh[bu][1][hB*8192 + ((wn & 127) + q4)*64 + ck0];
    rB[bu][1] = &Lsh[bu][1][hB*8192 + ((wn & 127) + q4)*64 + ck1];
  }

  f32x4 acc[8][4] = {};
  bf16x8 afr[8][2], bfr[4][2];

  auto readG1 = [&](int bu) {
    #pragma unroll
    for (int n=0;n<2;++n) {
      bfr[n][0] = *(const bf16x8*)(rB[bu][0] + n*1024);
      bfr[n][1] = *(const bf16x8*)(rB[bu][1] + n*1024);
    }
    #pragma unroll
    for (int m=0;m<4;++m) {
      afr[m][0] = *(const bf16x8*)(rA[bu][0] + m*1024);
      afr[m][1] = *(const bf16x8*)(rA[bu][1] + m*1024);
    }
  };

  if (VAR == 3) {
    // zero all LDS so MFMAs run on deterministic zeros (no staging in V3)
    int4v zz = {0,0,0,0};
    for (int i = t; i < 4096; i += 512) ((int4v*)&Lsh[0][0][0])[i] = zz;
    __builtin_amdgcn_s_barrier();
  } else {
    // prologue: B(0),A(0),B(1) staged
    stage(sB0, &Lsh[0][1][0],    0);
    stage(sB1, &Lsh[0][1][8192], 0);
    stage(sA0, &Lsh[0][0][0],    0);
    stage(sA1, &Lsh[0][0][8192], 0);
    if (KT > 1) {
      stage(sB0, &Lsh[1][1][0],    1);
      stage(sB1, &Lsh[1][1][8192], 1);
      if (VAR != 2) { asm volatile("s_waitcnt vmcnt(4)" ::: "memory"); }
    } else {
      if (VAR != 2) { asm volatile("s_waitcnt vmcnt(0)" ::: "memory"); }
    }
    SB0();
    if (VAR != 2) __builtin_amdgcn_s_barrier();
  }

  for (int rep = 0; rep < REP; ++rep) {
    if (VAR == 0 || VAR == 3) { readG1(0); SB0(); }
    for (int kt = 0; kt < KT; ++kt) {
      const int buf = kt & 1;
      const bool nb1 = (kt+1 < KT), nb2 = (kt+2 < KT);
      // ---- phase 1: issue G2; wait G1; Q1
      if (VAR == 0 || VAR == 3) {
        #pragma unroll
        for (int n=2;n<4;++n) {
          bfr[n][0] = *(const bf16x8*)(rB[buf][0] + n*1024);
          bfr[n][1] = *(const bf16x8*)(rB[buf][1] + n*1024);
        }
        SB0();
        asm volatile("s_waitcnt lgkmcnt(4)" ::: "memory"); SB0();
        __builtin_amdgcn_s_setprio(1);
        #pragma unroll
        for (int kk=0;kk<2;++kk)
          #pragma unroll
          for (int m=0;m<4;++m) {
            acc[m][0] = __builtin_amdgcn_mfma_f32_16x16x32_bf16(afr[m][kk], bfr[0][kk], acc[m][0], 0,0,0);
            acc[m][1] = __builtin_amdgcn_mfma_f32_16x16x32_bf16(afr[m][kk], bfr[1][kk], acc[m][1], 0,0,0);
          }
        __builtin_amdgcn_s_setprio(0);
        SB0();
        // ---- phase 2 reads: issue G3
        #pragma unroll
        for (int m=0;m<4;++m) {
          afr[4+m][0] = *(const bf16x8*)(rA[buf][0] + (4+m)*1024);
          afr[4+m][1] = *(const bf16x8*)(rA[buf][1] + (4+m)*1024);
        }
        SB0();
      }
      if (VAR != 3) {
        if (nb1) {
          stage(sA0, &Lsh[buf^1][0][0],    kt+1);
          stage(sA1, &Lsh[buf^1][0][8192], kt+1);
        }
        SB0();
      }
      if (VAR == 0 || VAR == 3) {
        asm volatile("s_waitcnt lgkmcnt(8)" ::: "memory"); SB0();
        __builtin_amdgcn_s_setprio(1);
        #pragma unroll
        for (int kk=0;kk<2;++kk)
          #pragma unroll
          for (int m=0;m<4;++m) {
            acc[m][2] = __builtin_amdgcn_mfma_f32_16x16x32_bf16(afr[m][kk], bfr[2][kk], acc[m][2], 0,0,0);
            acc[m][3] = __builtin_amdgcn_mfma_f32_16x16x32_bf16(afr[m][kk], bfr[3][kk], acc[m][3], 0,0,0);
          }
        __builtin_amdgcn_s_setprio(0);
        SB0();
      }
      if (VAR != 2) __builtin_amdgcn_s_barrier();
      // ---- phase 3: stage B(t+2); wait G3; Q3
      if (VAR != 3) {
        if (nb2) {
          stage(sB0, &Lsh[buf][1][0],    kt+2);
          stage(sB1, &Lsh[buf][1][8192], kt+2);
        }
        SB0();
      }
      if (VAR == 0 || VAR == 3) {
        asm volatile("s_waitcnt lgkmcnt(0)" ::: "memory"); SB0();
        __builtin_amdgcn_s_setprio(1);
        #pragma unroll
        for (int kk=0;kk<2;++kk)
          #pragma unroll
          for (int m=0;m<4;++m) {
            acc[4+m][0] = __builtin_amdgcn_mfma_f32_16x16x32_bf16(afr[4+m][kk], bfr[0][kk], acc[4+m][0], 0,0,0);
            acc[4+m][1] = __builtin_amdgcn_mfma_f32_16x16x32_bf16(afr[4+m][kk], bfr[1][kk], acc[4+m][1], 0,0,0);
          }
        __builtin_amdgcn_s_setprio(0);
        SB0();
        // ---- phase 4: Q4
        __builtin_amdgcn_s_setprio(1);
        #pragma unroll
        for (int kk=0;kk<2;++kk)
          #pragma unroll
          for (int m=0;m<4;++m) {
            acc[4+m][2] = __builtin_amdgcn_mfma_f32_16x16x32_bf16(afr[4+m][kk], bfr[2][kk], acc[4+m][2], 0,0,0);
            acc[4+m][3] = __builtin_amdgcn_mfma_f32_16x16x32_bf16(afr[4+m][kk], bfr[3][kk], acc[4+m][3], 0,0,0);
          }
        __builtin_amdgcn_s_setprio(0);
        SB0();
      }
      if (VAR == 0 || VAR == 1) {
        if (nb2) asm volatile("s_waitcnt vmcnt(4)" ::: "memory");
        else     asm volatile("s_waitcnt vmcnt(0)" ::: "memory");
        SB0();
      }
      if (VAR != 2) __builtin_amdgcn_s_barrier();
      if ((VAR == 0 || VAR == 3) && nb1) { readG1(buf^1); SB0(); }
    }
  }

  if (VAR == 0) {
    float bv[4];
    #pragma unroll
    for (int n=0;n<4;++n) bv[n] = bias[n0 + wn + n*16 + q4];
    #pragma unroll
    for (int m=0;m<8;++m) {
      #pragma unroll
      for (int j=0;j<4;++j) {
        const int r = m0 + wm + m*16 + (lane >> 4)*4 + j;
        if (r < M) {
          #pragma unroll
          for (int n=0;n<4;++n) {
            float v = acc[m][n][j] + bv[n];
            const size_t idx = (size_t)r*LDC + n0 + wn + n*16 + q4;
            if (EPI == 1) ((BF16*)Cv)[idx] = (BF16)v;
            else          ((float*)Cv)[idx] = v;
          }
        }
      }
    }
  } else {
    if (VAR == 2) { asm volatile("s_waitcnt vmcnt(0)" ::: "memory"); }
    float s = 0.f;
    #pragma unroll
    for (int m=0;m<8;++m)
      #pragma unroll
      for (int n=0;n<4;++n)
        #pragma unroll
        for (int j=0;j<4;++j) s += acc[m][n][j];
    diag[(size_t)blockIdx.x*512 + t] = s;
  }
}

// ---------------- attention: one block per (b,h) ----------------
__global__ __launch_bounds__(256,2) void attn_k(const BF16* __restrict__ QKV,
                                                BF16* __restrict__ O) {
  constexpr int KSTR = 72;
  constexpr int VSTR = 232;
  constexpr int PSTR = 40;
  __shared__ BF16 Kl[208*KSTR];
  __shared__ BF16 Vt[64*VSTR];
  __shared__ BF16 Pl[4][16*PSTR];
  const int bh = blockIdx.x;
  const int b = bh / 12, h = bh - b*12;
  const size_t rowbase = (size_t)b*197;
  const int t = threadIdx.x, lane = t & 63, wid = t >> 6;
  const BF16 z = (BF16)0.0f;
  for (int c = t; c < 208*8; c += 256) {
    int r = c >> 3, kc = c & 7;
    int4v val = {0,0,0,0};
    if (r < 197) val = *(const int4v*)(QKV + (rowbase + r)*N_QKV + 768 + h*64 + kc*8);
    *(int4v*)(Kl + r*KSTR + kc*8) = val;
  }
  for (int c = t; c < 208*8; c += 256) {
    int r = c >> 3, kc = c & 7;
    if (r < 197) {
      int4v val = *(const int4v*)(QKV + (rowbase + r)*N_QKV + 1536 + h*64 + kc*8);
      const BF16* pv = (const BF16*)&val;
      #pragma unroll
      for (int i=0;i<8;++i) Vt[(kc*8 + i)*VSTR + r] = pv[i];
    } else {
      #pragma unroll
      for (int i=0;i<8;++i) Vt[(kc*8 + i)*VSTR + r] = z;
    }
  }
  for (int c = t; c < 64*24; c += 256) {
    int d = c / 24, k2 = 208 + (c - d*24);
    Vt[d*VSTR + k2] = z;
  }
  __syncthreads();

  for (int chunk = wid; chunk < 13; chunk += 4) {
    const int q0 = chunk*16;
    int qr = q0 + (lane & 15);
    qr = (qr < 197) ? qr : 196;
    bf16x8 qa[2];
    #pragma unroll
    for (int kk=0;kk<2;++kk)
      qa[kk] = *(const bf16x8*)(QKV + (rowbase + qr)*N_QKV + h*64 + kk*32 + (lane >> 4)*8);
    f32x4 zf = {0.f,0.f,0.f,0.f};
    f32x4 s[14];
    #pragma unroll
    for (int nf=0;nf<14;++nf) s[nf] = zf;
    #pragma unroll
    for (int nf=0;nf<13;++nf) {
      #pragma unroll
      for (int kk=0;kk<2;++kk) {
        bf16x8 kb = *(const bf16x8*)(Kl + (nf*16 + (lane & 15))*KSTR + kk*32 + (lane >> 4)*8);
        s[nf] = __builtin_amdgcn_mfma_f32_16x16x32_bf16(qa[kk], kb, s[nf], 0, 0, 0);
      }
    }
    float mrow[4] = {-1e30f,-1e30f,-1e30f,-1e30f};
    float lrow[4] = {0.f,0.f,0.f,0.f};
    #pragma unroll
    for (int nf=0;nf<13;++nf) {
      const int cg = nf*16 + (lane & 15);
      #pragma unroll
      for (int j=0;j<4;++j) {
        float v = s[nf][j]*0.125f;
        v = (cg < 197) ? v : -1e30f;
        s[nf][j] = v;
        mrow[j] = fmaxf(mrow[j], v);
      }
    }
    #pragma unroll
    for (int j=0;j<4;++j) {
      #pragma unroll
      for (int off=1; off<16; off<<=1) mrow[j] = fmaxf(mrow[j], __shfl_xor(mrow[j], off));
    }
    #pragma unroll
    for (int nf=0;nf<13;++nf) {
      #pragma unroll
      for (int j=0;j<4;++j) {
        float p = __expf(s[nf][j] - mrow[j]);
        s[nf][j] = p;
        lrow[j] += p;
      }
    }
    #pragma unroll
    for (int j=0;j<4;++j) {
      #pragma unroll
      for (int off=1; off<16; off<<=1) lrow[j] += __shfl_xor(lrow[j], off);
    }
    BF16* P = &Pl[wid][0];
    f32x4 o[4] = {};
    #pragma unroll
    for (int kc=0; kc<7; ++kc) {
      asm volatile("s_waitcnt lgkmcnt(0)" ::: "memory");
      __builtin_amdgcn_sched_barrier(0);
      #pragma unroll
      for (int half=0; half<2; ++half) {
        const int nf = kc*2 + half;
        #pragma unroll
        for (int j=0;j<4;++j)
          P[((lane >> 4)*4 + j)*PSTR + half*16 + (lane & 15)] = (BF16)s[nf][j];
      }
      asm volatile("s_waitcnt lgkmcnt(0)" ::: "memory");
      __builtin_amdgcn_sched_barrier(0);
      bf16x8 pa = *(const bf16x8*)(P + (lane & 15)*PSTR + (lane >> 4)*8);
      #pragma unroll
      for (int df=0; df<4; ++df) {
        bf16x8 vb = *(const bf16x8*)(Vt + (df*16 + (lane & 15))*VSTR + kc*32 + (lane >> 4)*8);
        o[df] = __builtin_amdgcn_mfma_f32_16x16x32_bf16(pa, vb, o[df], 0, 0, 0);
      }
    }
    #pragma unroll
    for (int df=0; df<4; ++df) {
      #pragma unroll
      for (int j=0;j<4;++j) {
        const int r = q0 + (lane >> 4)*4 + j;
        if (r < 197) {
          float val = o[df][j] / lrow[j];
          O[(rowbase + r)*768 + h*64 + df*16 + (lane & 15)] = (BF16)val;
        }
      }
    }
  }
}

// ---------------- host launcher ----------------
extern "C" void kernel_launch(void* const* d_in, const int* in_sizes, int n_in,
                              void* d_out, int out_size, void* d_ws, size_t ws_size,
                              hipStream_t stream) {
  const float* tokens = (const float*)d_in[0];
  const float* qkv_w  = (const float*)d_in[1];
  const float* qkv_b  = (const float*)d_in[2];
  const float* proj_w = (const float*)d_in[3];
  const float* proj_b = (const float*)d_in[4];
  const float* gate_w = (const float*)d_in[5];
  const float* lora_a = (const float*)d_in[6];
  const float* lora_b = (const float*)d_in[7];

  size_t off = 0;
  auto take = [&](size_t bytes) {
    off = (off + 255) & ~(size_t)255;
    void* p = (char*)d_ws + off;
    off += bytes;
    return p;
  };
  BF16* Waug  = (BF16*)take((size_t)N_QKV*KAUG*2);
  BF16* Pb    = (BF16*)take((size_t)D_IN*D_IN*2);
  BF16* LAt   = (BF16*)take((size_t)64*D_IN*2);
  BF16* Aaug  = (BF16*)take((size_t)MTOK*KAUG*2);
  float* gates= (float*)take((size_t)MTOK*8*4);
  BF16* QKVb  = (BF16*)take((size_t)MTOK*N_QKV*2);
  BF16* Oc    = (BF16*)take((size_t)MTOK*D_IN*2);
  float* diag = (float*)take((size_t)450*512*4);

  prep_waug_k<<<(N_QKV*KAUG + 255)/256, 256, 0, stream>>>(qkv_w, lora_b, Waug);
  prep_pb_k<<<(D_IN*D_IN + 255)/256, 256, 0, stream>>>(proj_w, Pb);
  prep_lat_k<<<(64*D_IN + 255)/256, 256, 0, stream>>>(lora_a, LAt);
  token_prep_k<<<MTOK/4, 256, 0, stream>>>(tokens, gate_w, Aaug, gates);
  gemm_bt_k<64,64,0><<<dim3(1, MTOK/64), 256, 0, stream>>>(
      Aaug, KAUG, LAt, D_IN, gates, (void*)(Aaug + 768), KAUG, MTOK, D_IN);
  // augmented QKV GEMM (real)
  gemm8_k<1, 9, KAUG, KAUG, N_QKV, 0, 1><<<50*9, 512, 0, stream>>>(
      Aaug, Waug, qkv_b, (void*)QKVb, diag, MTOK, KAUG);
  attn_k<<<768, 256, 0, stream>>>(QKVb, Oc);
  // output projection
  gemm2_k<2, 6, D_IN, D_IN, D_IN><<<99*6, 256, 0, stream>>>(
      Oc, Pb, proj_b, d_out, MTOK, D_IN);

  // ---- diagnostics (results to scratch; interpret dur/4) ----
  // V1: stage-only with full wait/barrier skeleton
  gemm8_k<1, 9, KAUG, KAUG, N_QKV, 1, 4><<<50*9, 512, 0, stream>>>(
      Aaug, Waug, qkv_b, (void*)diag, diag, MTOK, KAUG);
  // V2: stage-only, no waits/barriers (raw stage throughput)
  gemm8_k<1, 9, KAUG, KAUG, N_QKV, 2, 4><<<50*9, 512, 0, stream>>>(
      Aaug, Waug, qkv_b, (void*)diag, diag, MTOK, KAUG);
  // V3: ds_read + MFMA only on zeroed LDS (no staging)
  gemm8_k<1, 9, KAUG, KAUG, N_QKV, 3, 4><<<50*9, 512, 0, stream>>>(
      Aaug, Waug, qkv_b, (void*)diag, diag, MTOK, KAUG);
}

// Round 7
// 178.825 us; speedup vs baseline: 3.0650x; 3.0650x over previous
//
#include <hip/hip_runtime.h>
#include <hip/hip_bf16.h>

typedef __hip_bfloat16 BF16;
typedef __attribute__((ext_vector_type(8))) short bf16x8;
typedef __attribute__((ext_vector_type(4))) float f32x4;
typedef __attribute__((ext_vector_type(4))) int int4v;

#define MTOK 12608      // 64*197 tokens
#define D_IN 768
#define KAUG 832        // 768 + 64 (E*R)
#define N_QKV 2304

#define AS1 __attribute__((address_space(1)))
#define AS3 __attribute__((address_space(3)))
#define SB0() __builtin_amdgcn_sched_barrier(0)

// ---------------- prep kernels ----------------
__global__ __launch_bounds__(256) void prep_waug_k(const float* __restrict__ qkv_w,
                                                   const float* __restrict__ lora_b,
                                                   BF16* __restrict__ Waug) {
  int idx = blockIdx.x*256 + threadIdx.x;
  if (idx >= N_QKV*KAUG) return;
  int k = idx / KAUG, c = idx - k*KAUG;
  float v = (c < D_IN) ? qkv_w[k*D_IN + c] : lora_b[(size_t)(c - D_IN)*N_QKV + k];
  Waug[idx] = (BF16)v;
}

__global__ __launch_bounds__(256) void prep_pb_k(const float* __restrict__ proj_w,
                                                 BF16* __restrict__ Pb) {
  int idx = blockIdx.x*256 + threadIdx.x;
  if (idx < D_IN*D_IN) Pb[idx] = (BF16)proj_w[idx];
}

__global__ __launch_bounds__(256) void prep_lat_k(const float* __restrict__ lora_a,
                                                  BF16* __restrict__ LAt) {
  int idx = blockIdx.x*256 + threadIdx.x;
  if (idx >= 64*D_IN) return;
  int j = idx / D_IN, d = idx - j*D_IN;
  LAt[idx] = (BF16)lora_a[(size_t)(j >> 3)*6144 + d*8 + (j & 7)];
}

// ---------------- token prep: bf16 cast + gate softmax ----------------
__global__ __launch_bounds__(256) void token_prep_k(const float* __restrict__ tokens,
                                                    const float* __restrict__ gate_w,
                                                    BF16* __restrict__ Aaug,
                                                    float* __restrict__ gates) {
  int w = blockIdx.x*4 + (threadIdx.x >> 6);
  int lane = threadIdx.x & 63;
  if (w >= MTOK) return;
  const float* x = tokens + (size_t)w*D_IN;
  float xv[12];
  #pragma unroll
  for (int i=0;i<12;++i) xv[i] = x[lane + 64*i];
  #pragma unroll
  for (int i=0;i<12;++i) Aaug[(size_t)w*KAUG + lane + 64*i] = (BF16)xv[i];
  float g[8] = {0,0,0,0,0,0,0,0};
  #pragma unroll
  for (int i=0;i<12;++i) {
    int d = lane + 64*i;
    #pragma unroll
    for (int e=0;e<8;++e) g[e] += xv[i]*gate_w[e*D_IN + d];
  }
  #pragma unroll
  for (int e=0;e<8;++e) {
    #pragma unroll
    for (int off=32; off; off >>= 1) g[e] += __shfl_xor(g[e], off);
  }
  float mx = g[0];
  #pragma unroll
  for (int e=1;e<8;++e) mx = fmaxf(mx, g[e]);
  float pe[8]; float ssum = 0.f;
  #pragma unroll
  for (int e=0;e<8;++e) { pe[e] = __expf(g[e]-mx); ssum += pe[e]; }
  float inv = 1.f/ssum;
  if (lane < 8) {
    float val = 0.f;
    #pragma unroll
    for (int e=0;e<8;++e) val = (lane==e) ? pe[e]*inv : val;
    gates[(size_t)w*8 + lane] = val;
  }
}

// ---------------- small 2-phase GEMM-BT (h-GEMM only) ----------------
template<int ROWS>
__device__ __forceinline__ void stage_bt(const BF16* __restrict__ g, int ldg, int row0, int M,
                                         BF16* lds, int kbase, int t) {
  constexpr int NIT = ROWS*8/256;
  #pragma unroll
  for (int it=0; it<NIT; ++it) {
    int c = it*256 + t;
    int r = c >> 3, kc = c & 7;
    int rg = row0 + r;
    rg = (rg < M) ? rg : (M-1);
    const BF16* gp = g + (size_t)rg*ldg + kbase + kc*8;
    BF16* lp = lds + (it*256 + (t & ~63))*8;
    __builtin_amdgcn_global_load_lds((const AS1 void*)gp, (AS3 void*)lp, 16, 0, 0);
  }
}

template<int BM, int BN, int EPI>
__global__ __launch_bounds__(256,3) void gemm_bt_k(const BF16* __restrict__ A, int lda,
                                                   const BF16* __restrict__ Bt, int ldb,
                                                   const float* __restrict__ aux,
                                                   void* __restrict__ Cv, int ldc,
                                                   int M, int K) {
  constexpr int BK = 64;
  constexpr int WM = BM/2, WN = BN/2;
  constexpr int MF = WM/16, NF = WN/16;
  __shared__ BF16 Al[BM*BK];
  __shared__ BF16 Bl[BN*BK];
  const int n0 = blockIdx.x*BN, m0 = blockIdx.y*BM;
  const int t = threadIdx.x, lane = t & 63, wid = t >> 6;
  const int wm = (wid >> 1)*WM, wn = (wid & 1)*WN;
  f32x4 acc[MF][NF] = {};
  const int KT = K/BK;
  for (int kt=0; kt<KT; ++kt) {
    stage_bt<BM>(A, lda, m0, M, Al, kt*BK, t);
    stage_bt<BN>(Bt, ldb, n0, 1<<30, Bl, kt*BK, t);
    __syncthreads();
    #pragma unroll
    for (int kk=0; kk<2; ++kk) {
      bf16x8 a[MF], b[NF];
      const int col = kk*32 + (lane >> 4)*8;
      #pragma unroll
      for (int m=0;m<MF;++m) a[m] = *(const bf16x8*)(Al + (wm + m*16 + (lane & 15))*BK + col);
      #pragma unroll
      for (int n=0;n<NF;++n) b[n] = *(const bf16x8*)(Bl + (wn + n*16 + (lane & 15))*BK + col);
      #pragma unroll
      for (int m=0;m<MF;++m)
        #pragma unroll
        for (int n=0;n<NF;++n)
          acc[m][n] = __builtin_amdgcn_mfma_f32_16x16x32_bf16(a[m], b[n], acc[m][n], 0, 0, 0);
    }
    __syncthreads();
  }
  #pragma unroll
  for (int m=0;m<MF;++m) {
    #pragma unroll
    for (int n=0;n<NF;++n) {
      const int rb = m0 + wm + m*16 + (lane >> 4)*4;
      const int c = n0 + wn + n*16 + (lane & 15);
      #pragma unroll
      for (int j=0;j<4;++j) {
        const int r = rb + j;
        if (r < M) {
          float v = acc[m][n][j];
          if (EPI == 0) {
            v *= aux[(size_t)r*8 + (c >> 3)];
            ((BF16*)Cv)[(size_t)r*ldc + c] = (BF16)v;
          } else if (EPI == 1) {
            v += aux[c];
            ((BF16*)Cv)[(size_t)r*ldc + c] = (BF16)v;
          } else {
            v += aux[c];
            ((float*)Cv)[(size_t)r*ldc + c] = v;
          }
        }
      }
    }
  }
}

// ---------------- 128x128 2-phase double-buffered GEMM-BT ----------------
// 2 blocks/CU (64 KiB LDS): cross-block TLP fills the wait stalls that
// bounded the 1-block/CU 256^2 schedules (round-6 ablation: V3 chain = 56us,
// stage = 13us, interaction = rest; single-block waits idle the CU).
// G4 swizzle: LDS elem (r,c) at r*64 + (c ^ ((r&7)<<3)); inverse on source.
template<int EPI, int NBN, int LDA, int LDB, int LDC>
__global__ __launch_bounds__(256,2) void gemm2_k(const BF16* __restrict__ A,
                                                 const BF16* __restrict__ Bt,
                                                 const float* __restrict__ bias,
                                                 void* __restrict__ Cv,
                                                 int M, int K) {
  __shared__ BF16 Lsh[2][2][8192];          // [buf][A,B][128*64]
  const int t = threadIdx.x, lane = t & 63, wid = t >> 6;
  const int nwg = gridDim.x;
  const int q8 = nwg >> 3, r8 = nwg & 7;
  const int xcd = blockIdx.x & 7, pos = blockIdx.x >> 3;
  const int wg = (xcd < r8 ? xcd*(q8+1) : r8*(q8+1) + (xcd - r8)*q8) + pos;
  const int mb = wg / NBN, nb = wg - mb*NBN;
  const int m0 = mb*128, n0 = nb*128;
  const int KT = K/64;
  const int q4 = lane & 15;
  const int wm = (wid >> 1)*64, wn = (wid & 1)*64;

  const BF16 *sA[4], *sB[4];
  #pragma unroll
  for (int it=0; it<4; ++it) {
    int c = it*256 + t;
    int r = c >> 3, p = c & 7;
    int sc = p ^ (r & 7);
    int ra = m0 + r; ra = ra < M ? ra : M-1;
    sA[it] = A  + (size_t)ra*LDA + sc*8;
    sB[it] = Bt + (size_t)(n0 + r)*LDB + sc*8;
  }
  auto stageAB = [&](int buf, int tile) {
    #pragma unroll
    for (int it=0; it<4; ++it)
      __builtin_amdgcn_global_load_lds((const AS1 void*)(sA[it] + tile*64),
        (AS3 void*)(&Lsh[buf][0][0] + (it*256 + (t & ~63))*8), 16, 0, 0);
    #pragma unroll
    for (int it=0; it<4; ++it)
      __builtin_amdgcn_global_load_lds((const AS1 void*)(sB[it] + tile*64),
        (AS3 void*)(&Lsh[buf][1][0] + (it*256 + (t & ~63))*8), 16, 0, 0);
  };

  const int sw = (q4 & 7) << 3;
  const int ck[2] = { (((lane >> 4)*8)) ^ sw, ((32 + (lane >> 4)*8)) ^ sw };

  f32x4 acc[4][4] = {};
  stageAB(0, 0);
  asm volatile("s_waitcnt vmcnt(0)" ::: "memory"); SB0();
  __builtin_amdgcn_s_barrier();

  for (int kt = 0; kt < KT; ++kt) {
    const int buf = kt & 1;
    if (kt+1 < KT) stageAB(buf^1, kt+1);
    bf16x8 a[4][2], b[4][2];
    #pragma unroll
    for (int m=0;m<4;++m)
      #pragma unroll
      for (int kk=0;kk<2;++kk)
        a[m][kk] = *(const bf16x8*)(&Lsh[buf][0][0] + (wm + m*16 + q4)*64 + ck[kk]);
    #pragma unroll
    for (int n=0;n<4;++n)
      #pragma unroll
      for (int kk=0;kk<2;++kk)
        b[n][kk] = *(const bf16x8*)(&Lsh[buf][1][0] + (wn + n*16 + q4)*64 + ck[kk]);
    asm volatile("s_waitcnt lgkmcnt(0)" ::: "memory"); SB0();
    __builtin_amdgcn_s_setprio(1);
    #pragma unroll
    for (int kk=0;kk<2;++kk)
      #pragma unroll
      for (int m=0;m<4;++m)
        #pragma unroll
        for (int n=0;n<4;++n)
          acc[m][n] = __builtin_amdgcn_mfma_f32_16x16x32_bf16(a[m][kk], b[n][kk], acc[m][n], 0,0,0);
    __builtin_amdgcn_s_setprio(0);
    SB0();
    if (kt+1 < KT) asm volatile("s_waitcnt vmcnt(0)" ::: "memory");
    SB0();
    __builtin_amdgcn_s_barrier();
  }

  float bv[4];
  #pragma unroll
  for (int n=0;n<4;++n) bv[n] = bias[n0 + wn + n*16 + q4];
  #pragma unroll
  for (int m=0;m<4;++m) {
    #pragma unroll
    for (int j=0;j<4;++j) {
      const int r = m0 + wm + m*16 + (lane >> 4)*4 + j;
      if (r < M) {
        #pragma unroll
        for (int n=0;n<4;++n) {
          float v = acc[m][n][j] + bv[n];
          const size_t idx = (size_t)r*LDC + n0 + wn + n*16 + q4;
          if (EPI == 1) ((BF16*)Cv)[idx] = (BF16)v;
          else          ((float*)Cv)[idx] = v;
        }
      }
    }
  }
}

// ---------------- attention: one block per (b,h) ----------------
__global__ __launch_bounds__(256,2) void attn_k(const BF16* __restrict__ QKV,
                                                BF16* __restrict__ O) {
  constexpr int KSTR = 72;
  constexpr int VSTR = 232;
  constexpr int PSTR = 40;
  __shared__ BF16 Kl[208*KSTR];
  __shared__ BF16 Vt[64*VSTR];
  __shared__ BF16 Pl[4][16*PSTR];
  const int bh = blockIdx.x;
  const int b = bh / 12, h = bh - b*12;
  const size_t rowbase = (size_t)b*197;
  const int t = threadIdx.x, lane = t & 63, wid = t >> 6;
  const BF16 z = (BF16)0.0f;
  for (int c = t; c < 208*8; c += 256) {
    int r = c >> 3, kc = c & 7;
    int4v val = {0,0,0,0};
    if (r < 197) val = *(const int4v*)(QKV + (rowbase + r)*N_QKV + 768 + h*64 + kc*8);
    *(int4v*)(Kl + r*KSTR + kc*8) = val;
  }
  for (int c = t; c < 208*8; c += 256) {
    int r = c >> 3, kc = c & 7;
    if (r < 197) {
      int4v val = *(const int4v*)(QKV + (rowbase + r)*N_QKV + 1536 + h*64 + kc*8);
      const BF16* pv = (const BF16*)&val;
      #pragma unroll
      for (int i=0;i<8;++i) Vt[(kc*8 + i)*VSTR + r] = pv[i];
    } else {
      #pragma unroll
      for (int i=0;i<8;++i) Vt[(kc*8 + i)*VSTR + r] = z;
    }
  }
  for (int c = t; c < 64*24; c += 256) {
    int d = c / 24, k2 = 208 + (c - d*24);
    Vt[d*VSTR + k2] = z;
  }
  __syncthreads();

  for (int chunk = wid; chunk < 13; chunk += 4) {
    const int q0 = chunk*16;
    int qr = q0 + (lane & 15);
    qr = (qr < 197) ? qr : 196;
    bf16x8 qa[2];
    #pragma unroll
    for (int kk=0;kk<2;++kk)
      qa[kk] = *(const bf16x8*)(QKV + (rowbase + qr)*N_QKV + h*64 + kk*32 + (lane >> 4)*8);
    f32x4 zf = {0.f,0.f,0.f,0.f};
    f32x4 s[14];
    #pragma unroll
    for (int nf=0;nf<14;++nf) s[nf] = zf;
    #pragma unroll
    for (int nf=0;nf<13;++nf) {
      #pragma unroll
      for (int kk=0;kk<2;++kk) {
        bf16x8 kb = *(const bf16x8*)(Kl + (nf*16 + (lane & 15))*KSTR + kk*32 + (lane >> 4)*8);
        s[nf] = __builtin_amdgcn_mfma_f32_16x16x32_bf16(qa[kk], kb, s[nf], 0, 0, 0);
      }
    }
    float mrow[4] = {-1e30f,-1e30f,-1e30f,-1e30f};
    float lrow[4] = {0.f,0.f,0.f,0.f};
    #pragma unroll
    for (int nf=0;nf<13;++nf) {
      const int cg = nf*16 + (lane & 15);
      #pragma unroll
      for (int j=0;j<4;++j) {
        float v = s[nf][j]*0.125f;
        v = (cg < 197) ? v : -1e30f;
        s[nf][j] = v;
        mrow[j] = fmaxf(mrow[j], v);
      }
    }
    #pragma unroll
    for (int j=0;j<4;++j) {
      #pragma unroll
      for (int off=1; off<16; off<<=1) mrow[j] = fmaxf(mrow[j], __shfl_xor(mrow[j], off));
    }
    #pragma unroll
    for (int nf=0;nf<13;++nf) {
      #pragma unroll
      for (int j=0;j<4;++j) {
        float p = __expf(s[nf][j] - mrow[j]);
        s[nf][j] = p;
        lrow[j] += p;
      }
    }
    #pragma unroll
    for (int j=0;j<4;++j) {
      #pragma unroll
      for (int off=1; off<16; off<<=1) lrow[j] += __shfl_xor(lrow[j], off);
    }
    BF16* P = &Pl[wid][0];
    f32x4 o[4] = {};
    #pragma unroll
    for (int kc=0; kc<7; ++kc) {
      asm volatile("s_waitcnt lgkmcnt(0)" ::: "memory");
      __builtin_amdgcn_sched_barrier(0);
      #pragma unroll
      for (int half=0; half<2; ++half) {
        const int nf = kc*2 + half;
        #pragma unroll
        for (int j=0;j<4;++j)
          P[((lane >> 4)*4 + j)*PSTR + half*16 + (lane & 15)] = (BF16)s[nf][j];
      }
      asm volatile("s_waitcnt lgkmcnt(0)" ::: "memory");
      __builtin_amdgcn_sched_barrier(0);
      bf16x8 pa = *(const bf16x8*)(P + (lane & 15)*PSTR + (lane >> 4)*8);
      #pragma unroll
      for (int df=0; df<4; ++df) {
        bf16x8 vb = *(const bf16x8*)(Vt + (df*16 + (lane & 15))*VSTR + kc*32 + (lane >> 4)*8);
        o[df] = __builtin_amdgcn_mfma_f32_16x16x32_bf16(pa, vb, o[df], 0, 0, 0);
      }
    }
    #pragma unroll
    for (int df=0; df<4; ++df) {
      #pragma unroll
      for (int j=0;j<4;++j) {
        const int r = q0 + (lane >> 4)*4 + j;
        if (r < 197) {
          float val = o[df][j] / lrow[j];
          O[(rowbase + r)*768 + h*64 + df*16 + (lane & 15)] = (BF16)val;
        }
      }
    }
  }
}

// ---------------- host launcher ----------------
extern "C" void kernel_launch(void* const* d_in, const int* in_sizes, int n_in,
                              void* d_out, int out_size, void* d_ws, size_t ws_size,
                              hipStream_t stream) {
  const float* tokens = (const float*)d_in[0];
  const float* qkv_w  = (const float*)d_in[1];
  const float* qkv_b  = (const float*)d_in[2];
  const float* proj_w = (const float*)d_in[3];
  const float* proj_b = (const float*)d_in[4];
  const float* gate_w = (const float*)d_in[5];
  const float* lora_a = (const float*)d_in[6];
  const float* lora_b = (const float*)d_in[7];

  size_t off = 0;
  auto take = [&](size_t bytes) {
    off = (off + 255) & ~(size_t)255;
    void* p = (char*)d_ws + off;
    off += bytes;
    return p;
  };
  BF16* Waug  = (BF16*)take((size_t)N_QKV*KAUG*2);
  BF16* Pb    = (BF16*)take((size_t)D_IN*D_IN*2);
  BF16* LAt   = (BF16*)take((size_t)64*D_IN*2);
  BF16* Aaug  = (BF16*)take((size_t)MTOK*KAUG*2);
  float* gates= (float*)take((size_t)MTOK*8*4);
  BF16* QKVb  = (BF16*)take((size_t)MTOK*N_QKV*2);
  BF16* Oc    = (BF16*)take((size_t)MTOK*D_IN*2);

  prep_waug_k<<<(N_QKV*KAUG + 255)/256, 256, 0, stream>>>(qkv_w, lora_b, Waug);
  prep_pb_k<<<(D_IN*D_IN + 255)/256, 256, 0, stream>>>(proj_w, Pb);
  prep_lat_k<<<(64*D_IN + 255)/256, 256, 0, stream>>>(lora_a, LAt);
  token_prep_k<<<MTOK/4, 256, 0, stream>>>(tokens, gate_w, Aaug, gates);
  gemm_bt_k<64,64,0><<<dim3(1, MTOK/64), 256, 0, stream>>>(
      Aaug, KAUG, LAt, D_IN, gates, (void*)(Aaug + 768), KAUG, MTOK, D_IN);
  // augmented QKV GEMM: 128^2 dbuf 2-phase, 2 blocks/CU (99 x 18 blocks)
  gemm2_k<1, 18, KAUG, KAUG, N_QKV><<<99*18, 256, 0, stream>>>(
      Aaug, Waug, qkv_b, (void*)QKVb, MTOK, KAUG);
  attn_k<<<768, 256, 0, stream>>>(QKVb, Oc);
  // output projection: same structure (99 x 6 blocks)
  gemm2_k<2, 6, D_IN, D_IN, D_IN><<<99*6, 256, 0, stream>>>(
      Oc, Pb, proj_b, d_out, MTOK, D_IN);
}